// Round 7
// baseline (234.673 us; speedup 1.0000x reference)
//
#include <hip/hip_runtime.h>
#include <hip/hip_bf16.h>
#include <hip/hip_fp16.h>

#define D 64
#define GRP 64              // rows per scale group
#define NG_E_MAX 8192       // max emb groups the LDS table supports
#define NG_P_MAX 2048       // max ph groups

typedef unsigned int   u32;
typedef unsigned short u16;
typedef float f32x4 __attribute__((ext_vector_type(4)));
typedef u32   u32x4 __attribute__((ext_vector_type(4)));

__device__ __forceinline__ float wave_max(float m) {
  m = fmaxf(m, __shfl_xor(m, 1, 64));
  m = fmaxf(m, __shfl_xor(m, 2, 64));
  m = fmaxf(m, __shfl_xor(m, 4, 64));
  m = fmaxf(m, __shfl_xor(m, 8, 64));
  m = fmaxf(m, __shfl_xor(m, 16, 64));
  m = fmaxf(m, __shfl_xor(m, 32, 64));
  return m;
}

__device__ __forceinline__ int dot4_i8(u32 a, u32 b, int acc) {
#if __has_builtin(__builtin_amdgcn_sdot4)
  return __builtin_amdgcn_sdot4((int)a, (int)b, acc, false);
#else
  acc += ((int)(a << 24) >> 24) * ((int)(b << 24) >> 24);
  acc += ((int)(a << 16) >> 24) * ((int)(b << 16) >> 24);
  acc += ((int)(a << 8) >> 24)  * ((int)(b << 8) >> 24);
  acc += ((int)a >> 24)         * ((int)b >> 24);
  return acc;
#endif
}

// ---------------- int8 group-scale path ----------------
// embq: [T][16] u32 (64 int8/row = 1 line); escale_g: [ngE] f16 (scale = m/127)
// phq:  [P][16] u32;                        pscale_g: [ngP] f16

// A1: group absmax over emb. One block per 64-row group; flat 4096-float span.
__global__ void __launch_bounds__(256) emb_group_scale_kernel(
    const float* __restrict__ emb, __half* __restrict__ escale_g, long total) {
  long base = (long)blockIdx.x * (GRP * D) + (long)threadIdx.x * 16;
  float m = 0.f;
#pragma unroll
  for (int k = 0; k < 4; ++k) {
    long off = base + (long)k * 4;
    if (off < total) {
      f32x4 v = __builtin_nontemporal_load((const f32x4*)(emb + off));
      m = fmaxf(m, fmaxf(fmaxf(fabsf(v.x), fabsf(v.y)),
                         fmaxf(fabsf(v.z), fabsf(v.w))));
    }
  }
  m = wave_max(m);
  __shared__ float red[4];
  if ((threadIdx.x & 63) == 0) red[threadIdx.x >> 6] = m;
  __syncthreads();
  if (threadIdx.x == 0) {
    float mm = fmaxf(fmaxf(red[0], red[1]), fmaxf(red[2], red[3]));
    escale_g[blockIdx.x] = __float2half(mm * (1.f / 127.f));
  }
}

// A3: quantize emb with group scale. 16 lanes/row.
__global__ void __launch_bounds__(256) quant_emb_kernel(
    const float* __restrict__ emb,
    const __half* __restrict__ escale_g,
    u32* __restrict__ embq, int T) {
  int tid = blockIdx.x * blockDim.x + threadIdx.x;
  int t = tid >> 4;
  int l = tid & 15;
  if (t >= T) return;
  f32x4 v = __builtin_nontemporal_load((const f32x4*)(emb + (size_t)t * D) + l);
  float sv = __half2float(escale_g[t >> 6]);
  float inv = (sv > 0.f) ? 1.f / sv : 0.f;
  int q0 = __float2int_rn(v.x * inv);
  int q1 = __float2int_rn(v.y * inv);
  int q2 = __float2int_rn(v.z * inv);
  int q3 = __float2int_rn(v.w * inv);
  u32 w = (u32)(q0 & 0xFF) | ((u32)(q1 & 0xFF) << 8) |
          ((u32)(q2 & 0xFF) << 16) | ((u32)(q3 & 0xFF) << 24);
  embq[(size_t)t * 16 + l] = w;
}

// B: build + quantize ph, one block per 64-ph-row group (block-local scale).
__global__ void __launch_bounds__(256) ph_build_kernel(
    const u32* __restrict__ embq,
    const __half* __restrict__ escale_g,
    const int* __restrict__ sampled,   // [P,2]
    u32* __restrict__ phq,
    __half* __restrict__ pscale_g,
    int P) {
  int g = blockIdx.x;
  int r = threadIdx.x >> 2;     // row within group
  int l = threadIdx.x & 3;
  int p = g * GRP + r;
  bool valid = (p < P);
  float f[16];
  float m = 0.f;
  if (valid) {
    int s0 = sampled[2 * p + 0];
    int s1 = sampled[2 * p + 1];
    u32x4 q0 = *(const u32x4*)(embq + (size_t)s0 * 16 + l * 4);
    u32x4 q1 = *(const u32x4*)(embq + (size_t)s1 * 16 + l * 4);
    float c0 = 0.5f * __half2float(escale_g[s0 >> 6]);
    float c1 = 0.5f * __half2float(escale_g[s1 >> 6]);
#pragma unroll
    for (int k = 0; k < 4; ++k) {
      u32 a = q0[k], b = q1[k];
      f[4 * k + 0] = c0 * (float)((int)(a << 24) >> 24) + c1 * (float)((int)(b << 24) >> 24);
      f[4 * k + 1] = c0 * (float)((int)(a << 16) >> 24) + c1 * (float)((int)(b << 16) >> 24);
      f[4 * k + 2] = c0 * (float)((int)(a << 8) >> 24)  + c1 * (float)((int)(b << 8) >> 24);
      f[4 * k + 3] = c0 * (float)((int)a >> 24)         + c1 * (float)((int)b >> 24);
    }
#pragma unroll
    for (int i = 0; i < 16; ++i) m = fmaxf(m, fabsf(f[i]));
  } else {
#pragma unroll
    for (int i = 0; i < 16; ++i) f[i] = 0.f;
  }
  m = wave_max(m);
  __shared__ float red[4];
  __shared__ float bscale;
  if ((threadIdx.x & 63) == 0) red[threadIdx.x >> 6] = m;
  __syncthreads();
  if (threadIdx.x == 0) {
    float mm = fmaxf(fmaxf(red[0], red[1]), fmaxf(red[2], red[3]));
    __half h = __float2half(mm * (1.f / 127.f));
    pscale_g[g] = h;
    bscale = __half2float(h);           // use roundtripped value for consistency
  }
  __syncthreads();
  if (valid) {
    float sv = bscale;
    float inv = (sv > 0.f) ? 1.f / sv : 0.f;
    u32x4 w;
#pragma unroll
    for (int k = 0; k < 4; ++k) {
      int a0 = __float2int_rn(f[4 * k + 0] * inv);
      int a1 = __float2int_rn(f[4 * k + 1] * inv);
      int a2 = __float2int_rn(f[4 * k + 2] * inv);
      int a3 = __float2int_rn(f[4 * k + 3] * inv);
      w[k] = (u32)(a0 & 0xFF) | ((u32)(a1 & 0xFF) << 8) |
             ((u32)(a2 & 0xFF) << 16) | ((u32)(a3 & 0xFF) << 24);
    }
    *(u32x4*)(phq + (size_t)p * 16 + l * 4) = w;
  }
}

// C: edge scores. Scale tables in LDS (zero vmem requests for scales).
// 4 lanes/edge, 2 edges per group-iteration for MLP. embq: sc1+nt bypass.
__global__ void __launch_bounds__(256) edge_score_kernel(
    const u32* __restrict__ phq,
    const __half* __restrict__ pscale_g,
    const u32* __restrict__ embq,
    const __half* __restrict__ escale_g,
    const int* __restrict__ esrc,
    const int* __restrict__ edst,
    float* __restrict__ out,
    int E, int ngE, int ngP) {
  __shared__ __half lds_es[NG_E_MAX];
  __shared__ __half lds_ps[NG_P_MAX];
  for (int i = threadIdx.x; i < ngE; i += 256) lds_es[i] = escale_g[i];
  for (int i = threadIdx.x; i < ngP; i += 256) lds_ps[i] = pscale_g[i];
  __syncthreads();

  long nPair = ((long)E + 1) >> 1;
  long total = nPair * 4;
  long stride = (long)gridDim.x * 256;
  for (long idx = (long)blockIdx.x * 256 + threadIdx.x; idx < total; idx += stride) {
    long pr = idx >> 2;
    int l = (int)(idx & 3);
    int e0 = (int)(pr << 1);
    int e1 = e0 + 1;
    bool has1 = (e1 < E);
    int ec = has1 ? e1 : e0;
    int s0 = __builtin_nontemporal_load(esrc + e0);
    int d0 = __builtin_nontemporal_load(edst + e0);
    int s1 = __builtin_nontemporal_load(esrc + ec);
    int d1 = __builtin_nontemporal_load(edst + ec);

    u32x4 qe0, qe1;
    const u32* ea0 = embq + (size_t)d0 * 16 + l * 4;
    const u32* ea1 = embq + (size_t)d1 * 16 + l * 4;
    asm volatile("global_load_dwordx4 %0, %1, off sc1 nt" : "=&v"(qe0) : "v"(ea0));
    asm volatile("global_load_dwordx4 %0, %1, off sc1 nt" : "=&v"(qe1) : "v"(ea1));
    u32x4 qp0 = *(const u32x4*)(phq + (size_t)s0 * 16 + l * 4);
    u32x4 qp1 = *(const u32x4*)(phq + (size_t)s1 * 16 + l * 4);
    asm volatile("s_waitcnt vmcnt(0)"
                 : "+v"(qp0), "+v"(qp1), "+v"(qe0), "+v"(qe1) :: "memory");
    __builtin_amdgcn_sched_barrier(0);

    int a0 = 0, a1 = 0;
#pragma unroll
    for (int k = 0; k < 4; ++k) {
      a0 = dot4_i8(qp0[k], qe0[k], a0);
      a1 = dot4_i8(qp1[k], qe1[k], a1);
    }
    a0 += __shfl_xor(a0, 1, 64);
    a0 += __shfl_xor(a0, 2, 64);
    a1 += __shfl_xor(a1, 1, 64);
    a1 += __shfl_xor(a1, 2, 64);
    if (l == 0) {
      float o0 = (float)a0 * __half2float(lds_ps[s0 >> 6]) *
                 __half2float(lds_es[d0 >> 6]);
      __builtin_nontemporal_store(o0, out + e0);
      if (has1) {
        float o1 = (float)a1 * __half2float(lds_ps[s1 >> 6]) *
                   __half2float(lds_es[d1 >> 6]);
        __builtin_nontemporal_store(o1, out + e1);
      }
    }
  }
}

// ---------------- f32 fallback (ws too small / sizes exceed LDS tables) ----

__global__ void __launch_bounds__(256) ph_build_f32_kernel(
    const float* __restrict__ track_emb, const int* __restrict__ sampled,
    float* __restrict__ ph, int P) {
  int tid = blockIdx.x * blockDim.x + threadIdx.x;
  int p = tid >> 4, l = tid & 15;
  if (p >= P) return;
  int s0 = sampled[2 * p + 0], s1 = sampled[2 * p + 1];
  const float4 a = *(const float4*)(track_emb + (size_t)s0 * D + l * 4);
  const float4 b = *(const float4*)(track_emb + (size_t)s1 * D + l * 4);
  float4 r;
  r.x = 0.5f * (a.x + b.x); r.y = 0.5f * (a.y + b.y);
  r.z = 0.5f * (a.z + b.z); r.w = 0.5f * (a.w + b.w);
  *(float4*)(ph + (size_t)p * D + l * 4) = r;
}

__global__ void __launch_bounds__(256) edge_score_f32_kernel(
    const float* __restrict__ ph, const float* __restrict__ track_emb,
    const int* __restrict__ esrc, const int* __restrict__ edst,
    float* __restrict__ out, int E) {
  int tid = blockIdx.x * blockDim.x + threadIdx.x;
  int e = tid >> 4, l = tid & 15;
  if (e >= E) return;
  int s = esrc[e], d = edst[e];
  const float4 a = *(const float4*)(ph + (size_t)s * D + l * 4);
  const float4 b = *(const float4*)(track_emb + (size_t)d * D + l * 4);
  float v = a.x * b.x + a.y * b.y + a.z * b.z + a.w * b.w;
  v += __shfl_xor(v, 1, 64);
  v += __shfl_xor(v, 2, 64);
  v += __shfl_xor(v, 4, 64);
  if (l == 0) out[e] = v;
}

extern "C" void kernel_launch(void* const* d_in, const int* in_sizes, int n_in,
                              void* d_out, int out_size, void* d_ws, size_t ws_size,
                              hipStream_t stream) {
  const float* track_emb = (const float*)d_in[0];   // [T, 64] f32
  const int*   edge_src  = (const int*)d_in[1];     // [E]
  const int*   edge_dst  = (const int*)d_in[2];     // [E]
  const int*   sampled   = (const int*)d_in[3];     // [P, 2]
  float* out = (float*)d_out;                       // [E] f32

  const int E = in_sizes[1];
  const int P = in_sizes[3] / 2;
  const int T = in_sizes[0] / D;

  const int ngE = (T + GRP - 1) / GRP;
  const int ngP = (P + GRP - 1) / GRP;

  const size_t embq_bytes   = (size_t)T * 16 * sizeof(u32);          // 32 MB
  const size_t escale_bytes = ((size_t)ngE * 2 + 255) & ~(size_t)255;
  const size_t phq_bytes    = (size_t)P * 16 * sizeof(u32);          // 6.4 MB
  const size_t pscale_bytes = ((size_t)ngP * 2 + 255) & ~(size_t)255;
  const size_t need = embq_bytes + escale_bytes + phq_bytes + pscale_bytes;

  if (ws_size >= need && ngE <= NG_E_MAX && ngP <= NG_P_MAX) {
    char* w = (char*)d_ws;
    u32*    embq     = (u32*)w;     w += embq_bytes;
    __half* escale_g = (__half*)w;  w += escale_bytes;
    u32*    phq      = (u32*)w;     w += phq_bytes;
    __half* pscale_g = (__half*)w;

    // A1: per-group absmax of emb
    emb_group_scale_kernel<<<ngE, 256, 0, stream>>>(track_emb, escale_g,
                                                    (long)T * D);
    // A3: quantize emb with group scales
    {
      long t = (long)T * 16;
      int blocks = (int)((t + 255) / 256);
      quant_emb_kernel<<<blocks, 256, 0, stream>>>(track_emb, escale_g, embq, T);
    }
    // B: build + quantize ph (block-local group scale)
    ph_build_kernel<<<ngP, 256, 0, stream>>>(embq, escale_g, sampled,
                                             phq, pscale_g, P);
    // C: edge scores, fully-resident grid (8 blocks/CU by 20KB LDS)
    {
      long total = (((long)E + 1) >> 1) * 4;
      int blocks = (int)((total + 255) / 256);
      if (blocks > 2048) blocks = 2048;
      edge_score_kernel<<<blocks, 256, 0, stream>>>(
          phq, pscale_g, embq, escale_g, edge_src, edge_dst, out, E, ngE, ngP);
    }
  } else {
    // fallback: f32 path
    float* ph = (float*)d_ws;
    {
      long t = (long)P * 16;
      int blocks = (int)((t + 255) / 256);
      ph_build_f32_kernel<<<blocks, 256, 0, stream>>>(track_emb, sampled, ph, P);
    }
    {
      long t = (long)E * 16;
      int blocks = (int)((t + 255) / 256);
      edge_score_f32_kernel<<<blocks, 256, 0, stream>>>(ph, track_emb, edge_src,
                                                        edge_dst, out, E);
    }
  }
}

// Round 8
// 168.049 us; speedup vs baseline: 1.3965x; 1.3965x over previous
//
#include <hip/hip_runtime.h>
#include <hip/hip_bf16.h>
#include <hip/hip_fp16.h>

#define D 64
#define GRP 64              // rows per scale group
#define NG_E_MAX 8192       // max emb groups the LDS table supports
#define NG_P_MAX 2048       // max ph groups

typedef unsigned int   u32;
typedef unsigned short u16;
typedef float f32x4 __attribute__((ext_vector_type(4)));
typedef u32   u32x4 __attribute__((ext_vector_type(4)));

__device__ __forceinline__ float wave_max(float m) {
  m = fmaxf(m, __shfl_xor(m, 1, 64));
  m = fmaxf(m, __shfl_xor(m, 2, 64));
  m = fmaxf(m, __shfl_xor(m, 4, 64));
  m = fmaxf(m, __shfl_xor(m, 8, 64));
  m = fmaxf(m, __shfl_xor(m, 16, 64));
  m = fmaxf(m, __shfl_xor(m, 32, 64));
  return m;
}

__device__ __forceinline__ int dot4_i8(u32 a, u32 b, int acc) {
#if __has_builtin(__builtin_amdgcn_sdot4)
  return __builtin_amdgcn_sdot4((int)a, (int)b, acc, false);
#else
  acc += ((int)(a << 24) >> 24) * ((int)(b << 24) >> 24);
  acc += ((int)(a << 16) >> 24) * ((int)(b << 16) >> 24);
  acc += ((int)(a << 8) >> 24)  * ((int)(b << 8) >> 24);
  acc += ((int)a >> 24)         * ((int)b >> 24);
  return acc;
#endif
}

// ---------------- int8 group-scale path ----------------
// embq: [T][16] u32 (64 int8/row = 1 line); escale_g: [ngE] f16 (scale = m/127)
// phq:  [P][16] u32;                        pscale_g: [ngP] f16

// A (fused): one block per 64-row group (4096 floats, 16 KB contiguous).
// Pass: coalesced NT read -> group absmax (LDS reduce) -> quantize from regs
// -> coalesced NT write. ONE stream over emb instead of R7's two.
__global__ void __launch_bounds__(256) quant_emb_fused_kernel(
    const float* __restrict__ emb,
    u32* __restrict__ embq,
    __half* __restrict__ escale_g,
    long total /* = T*D floats */) {
  long base = (long)blockIdx.x * (GRP * D);
  f32x4 v[4];
  float m = 0.f;
#pragma unroll
  for (int k = 0; k < 4; ++k) {
    long off = base + (long)k * 1024 + (long)threadIdx.x * 4;
    if (off < total) {
      v[k] = __builtin_nontemporal_load((const f32x4*)(emb + off));
      m = fmaxf(m, fmaxf(fmaxf(fabsf(v[k].x), fabsf(v[k].y)),
                         fmaxf(fabsf(v[k].z), fabsf(v[k].w))));
    } else {
      v[k] = (f32x4){0.f, 0.f, 0.f, 0.f};
    }
  }
  m = wave_max(m);
  __shared__ float red[4];
  __shared__ float bscale;
  if ((threadIdx.x & 63) == 0) red[threadIdx.x >> 6] = m;
  __syncthreads();
  if (threadIdx.x == 0) {
    float mm = fmaxf(fmaxf(red[0], red[1]), fmaxf(red[2], red[3]));
    __half h = __float2half(mm * (1.f / 127.f));
    escale_g[blockIdx.x] = h;
    bscale = __half2float(h);          // roundtripped for consistency
  }
  __syncthreads();
  float sv = bscale;
  float inv = (sv > 0.f) ? 1.f / sv : 0.f;
#pragma unroll
  for (int k = 0; k < 4; ++k) {
    long off = base + (long)k * 1024 + (long)threadIdx.x * 4;
    if (off < total) {
      int q0 = __float2int_rn(v[k].x * inv);
      int q1 = __float2int_rn(v[k].y * inv);
      int q2 = __float2int_rn(v[k].z * inv);
      int q3 = __float2int_rn(v[k].w * inv);
      u32 w = (u32)(q0 & 0xFF) | ((u32)(q1 & 0xFF) << 8) |
              ((u32)(q2 & 0xFF) << 16) | ((u32)(q3 & 0xFF) << 24);
      __builtin_nontemporal_store(w, embq + (off >> 2));
    }
  }
}

// B: build + quantize ph, one block per 64-ph-row group (block-local scale).
__global__ void __launch_bounds__(256) ph_build_kernel(
    const u32* __restrict__ embq,
    const __half* __restrict__ escale_g,
    const int* __restrict__ sampled,   // [P,2]
    u32* __restrict__ phq,
    __half* __restrict__ pscale_g,
    int P) {
  int g = blockIdx.x;
  int r = threadIdx.x >> 2;     // row within group
  int l = threadIdx.x & 3;
  int p = g * GRP + r;
  bool valid = (p < P);
  float f[16];
  float m = 0.f;
  if (valid) {
    int s0 = sampled[2 * p + 0];
    int s1 = sampled[2 * p + 1];
    u32x4 q0 = *(const u32x4*)(embq + (size_t)s0 * 16 + l * 4);
    u32x4 q1 = *(const u32x4*)(embq + (size_t)s1 * 16 + l * 4);
    float c0 = 0.5f * __half2float(escale_g[s0 >> 6]);
    float c1 = 0.5f * __half2float(escale_g[s1 >> 6]);
#pragma unroll
    for (int k = 0; k < 4; ++k) {
      u32 a = q0[k], b = q1[k];
      f[4 * k + 0] = c0 * (float)((int)(a << 24) >> 24) + c1 * (float)((int)(b << 24) >> 24);
      f[4 * k + 1] = c0 * (float)((int)(a << 16) >> 24) + c1 * (float)((int)(b << 16) >> 24);
      f[4 * k + 2] = c0 * (float)((int)(a << 8) >> 24)  + c1 * (float)((int)(b << 8) >> 24);
      f[4 * k + 3] = c0 * (float)((int)a >> 24)         + c1 * (float)((int)b >> 24);
    }
#pragma unroll
    for (int i = 0; i < 16; ++i) m = fmaxf(m, fabsf(f[i]));
  } else {
#pragma unroll
    for (int i = 0; i < 16; ++i) f[i] = 0.f;
  }
  m = wave_max(m);
  __shared__ float red[4];
  __shared__ float bscale;
  if ((threadIdx.x & 63) == 0) red[threadIdx.x >> 6] = m;
  __syncthreads();
  if (threadIdx.x == 0) {
    float mm = fmaxf(fmaxf(red[0], red[1]), fmaxf(red[2], red[3]));
    __half h = __float2half(mm * (1.f / 127.f));
    pscale_g[g] = h;
    bscale = __half2float(h);
  }
  __syncthreads();
  if (valid) {
    float sv = bscale;
    float inv = (sv > 0.f) ? 1.f / sv : 0.f;
    u32x4 w;
#pragma unroll
    for (int k = 0; k < 4; ++k) {
      int a0 = __float2int_rn(f[4 * k + 0] * inv);
      int a1 = __float2int_rn(f[4 * k + 1] * inv);
      int a2 = __float2int_rn(f[4 * k + 2] * inv);
      int a3 = __float2int_rn(f[4 * k + 3] * inv);
      w[k] = (u32)(a0 & 0xFF) | ((u32)(a1 & 0xFF) << 8) |
             ((u32)(a2 & 0xFF) << 16) | ((u32)(a3 & 0xFF) << 24);
    }
    *(u32x4*)(phq + (size_t)p * 16 + l * 4) = w;
  }
}

// C: edge scores. Scale tables in LDS (zero vmem requests for scales).
// 4 lanes/edge, 2 edges per group-iteration for MLP. embq: sc1+nt bypass.
__global__ void __launch_bounds__(256) edge_score_kernel(
    const u32* __restrict__ phq,
    const __half* __restrict__ pscale_g,
    const u32* __restrict__ embq,
    const __half* __restrict__ escale_g,
    const int* __restrict__ esrc,
    const int* __restrict__ edst,
    float* __restrict__ out,
    int E, int ngE, int ngP) {
  __shared__ __half lds_es[NG_E_MAX];
  __shared__ __half lds_ps[NG_P_MAX];
  for (int i = threadIdx.x; i < ngE; i += 256) lds_es[i] = escale_g[i];
  for (int i = threadIdx.x; i < ngP; i += 256) lds_ps[i] = pscale_g[i];
  __syncthreads();

  long nPair = ((long)E + 1) >> 1;
  long total = nPair * 4;
  long stride = (long)gridDim.x * 256;
  for (long idx = (long)blockIdx.x * 256 + threadIdx.x; idx < total; idx += stride) {
    long pr = idx >> 2;
    int l = (int)(idx & 3);
    int e0 = (int)(pr << 1);
    int e1 = e0 + 1;
    bool has1 = (e1 < E);
    int ec = has1 ? e1 : e0;
    int s0 = __builtin_nontemporal_load(esrc + e0);
    int d0 = __builtin_nontemporal_load(edst + e0);
    int s1 = __builtin_nontemporal_load(esrc + ec);
    int d1 = __builtin_nontemporal_load(edst + ec);

    u32x4 qe0, qe1;
    const u32* ea0 = embq + (size_t)d0 * 16 + l * 4;
    const u32* ea1 = embq + (size_t)d1 * 16 + l * 4;
    asm volatile("global_load_dwordx4 %0, %1, off sc1 nt" : "=&v"(qe0) : "v"(ea0));
    asm volatile("global_load_dwordx4 %0, %1, off sc1 nt" : "=&v"(qe1) : "v"(ea1));
    u32x4 qp0 = *(const u32x4*)(phq + (size_t)s0 * 16 + l * 4);
    u32x4 qp1 = *(const u32x4*)(phq + (size_t)s1 * 16 + l * 4);
    asm volatile("s_waitcnt vmcnt(0)"
                 : "+v"(qp0), "+v"(qp1), "+v"(qe0), "+v"(qe1) :: "memory");
    __builtin_amdgcn_sched_barrier(0);

    int a0 = 0, a1 = 0;
#pragma unroll
    for (int k = 0; k < 4; ++k) {
      a0 = dot4_i8(qp0[k], qe0[k], a0);
      a1 = dot4_i8(qp1[k], qe1[k], a1);
    }
    a0 += __shfl_xor(a0, 1, 64);
    a0 += __shfl_xor(a0, 2, 64);
    a1 += __shfl_xor(a1, 1, 64);
    a1 += __shfl_xor(a1, 2, 64);
    if (l == 0) {
      float o0 = (float)a0 * __half2float(lds_ps[s0 >> 6]) *
                 __half2float(lds_es[d0 >> 6]);
      __builtin_nontemporal_store(o0, out + e0);
      if (has1) {
        float o1 = (float)a1 * __half2float(lds_ps[s1 >> 6]) *
                   __half2float(lds_es[d1 >> 6]);
        __builtin_nontemporal_store(o1, out + e1);
      }
    }
  }
}

// ---------------- f32 fallback (ws too small / sizes exceed LDS tables) ----

__global__ void __launch_bounds__(256) ph_build_f32_kernel(
    const float* __restrict__ track_emb, const int* __restrict__ sampled,
    float* __restrict__ ph, int P) {
  int tid = blockIdx.x * blockDim.x + threadIdx.x;
  int p = tid >> 4, l = tid & 15;
  if (p >= P) return;
  int s0 = sampled[2 * p + 0], s1 = sampled[2 * p + 1];
  const float4 a = *(const float4*)(track_emb + (size_t)s0 * D + l * 4);
  const float4 b = *(const float4*)(track_emb + (size_t)s1 * D + l * 4);
  float4 r;
  r.x = 0.5f * (a.x + b.x); r.y = 0.5f * (a.y + b.y);
  r.z = 0.5f * (a.z + b.z); r.w = 0.5f * (a.w + b.w);
  *(float4*)(ph + (size_t)p * D + l * 4) = r;
}

__global__ void __launch_bounds__(256) edge_score_f32_kernel(
    const float* __restrict__ ph, const float* __restrict__ track_emb,
    const int* __restrict__ esrc, const int* __restrict__ edst,
    float* __restrict__ out, int E) {
  int tid = blockIdx.x * blockDim.x + threadIdx.x;
  int e = tid >> 4, l = tid & 15;
  if (e >= E) return;
  int s = esrc[e], d = edst[e];
  const float4 a = *(const float4*)(ph + (size_t)s * D + l * 4);
  const float4 b = *(const float4*)(track_emb + (size_t)d * D + l * 4);
  float v = a.x * b.x + a.y * b.y + a.z * b.z + a.w * b.w;
  v += __shfl_xor(v, 1, 64);
  v += __shfl_xor(v, 2, 64);
  v += __shfl_xor(v, 4, 64);
  if (l == 0) out[e] = v;
}

extern "C" void kernel_launch(void* const* d_in, const int* in_sizes, int n_in,
                              void* d_out, int out_size, void* d_ws, size_t ws_size,
                              hipStream_t stream) {
  const float* track_emb = (const float*)d_in[0];   // [T, 64] f32
  const int*   edge_src  = (const int*)d_in[1];     // [E]
  const int*   edge_dst  = (const int*)d_in[2];     // [E]
  const int*   sampled   = (const int*)d_in[3];     // [P, 2]
  float* out = (float*)d_out;                       // [E] f32

  const int E = in_sizes[1];
  const int P = in_sizes[3] / 2;
  const int T = in_sizes[0] / D;

  const int ngE = (T + GRP - 1) / GRP;
  const int ngP = (P + GRP - 1) / GRP;

  const size_t embq_bytes   = (size_t)T * 16 * sizeof(u32);          // 32 MB
  const size_t escale_bytes = ((size_t)ngE * 2 + 255) & ~(size_t)255;
  const size_t phq_bytes    = (size_t)P * 16 * sizeof(u32);          // 6.4 MB
  const size_t pscale_bytes = ((size_t)ngP * 2 + 255) & ~(size_t)255;
  const size_t need = embq_bytes + escale_bytes + phq_bytes + pscale_bytes;

  if (ws_size >= need && ngE <= NG_E_MAX && ngP <= NG_P_MAX) {
    char* w = (char*)d_ws;
    u32*    embq     = (u32*)w;     w += embq_bytes;
    __half* escale_g = (__half*)w;  w += escale_bytes;
    u32*    phq      = (u32*)w;     w += phq_bytes;
    __half* pscale_g = (__half*)w;

    // A: fused group-absmax + quantize, ONE pass over emb
    quant_emb_fused_kernel<<<ngE, 256, 0, stream>>>(track_emb, embq, escale_g,
                                                    (long)T * D);
    // B: build + quantize ph (block-local group scale)
    ph_build_kernel<<<ngP, 256, 0, stream>>>(embq, escale_g, sampled,
                                             phq, pscale_g, P);
    // C: edge scores, fully-resident grid (8 blocks/CU by 20KB LDS)
    {
      long total = (((long)E + 1) >> 1) * 4;
      int blocks = (int)((total + 255) / 256);
      if (blocks > 2048) blocks = 2048;
      edge_score_kernel<<<blocks, 256, 0, stream>>>(
          phq, pscale_g, embq, escale_g, edge_src, edge_dst, out, E, ngE, ngP);
    }
  } else {
    // fallback: f32 path
    float* ph = (float*)d_ws;
    {
      long t = (long)P * 16;
      int blocks = (int)((t + 255) / 256);
      ph_build_f32_kernel<<<blocks, 256, 0, stream>>>(track_emb, sampled, ph, P);
    }
    {
      long t = (long)E * 16;
      int blocks = (int)((t + 255) / 256);
      edge_score_f32_kernel<<<blocks, 256, 0, stream>>>(ph, track_emb, edge_src,
                                                        edge_dst, out, E);
    }
  }
}

// Round 10
// 161.863 us; speedup vs baseline: 1.4498x; 1.0382x over previous
//
#include <hip/hip_runtime.h>
#include <hip/hip_bf16.h>
#include <hip/hip_fp16.h>

#define D 64
#define GRP 64              // rows per scale group
#define NG_E_MAX 8192       // max emb groups the LDS table supports
#define NG_P_MAX 2048       // max ph groups

typedef unsigned int   u32;
typedef unsigned short u16;
typedef float f32x4 __attribute__((ext_vector_type(4)));
typedef u32   u32x4 __attribute__((ext_vector_type(4)));
typedef int   i32x4 __attribute__((ext_vector_type(4)));

__device__ __forceinline__ float wave_max(float m) {
  m = fmaxf(m, __shfl_xor(m, 1, 64));
  m = fmaxf(m, __shfl_xor(m, 2, 64));
  m = fmaxf(m, __shfl_xor(m, 4, 64));
  m = fmaxf(m, __shfl_xor(m, 8, 64));
  m = fmaxf(m, __shfl_xor(m, 16, 64));
  m = fmaxf(m, __shfl_xor(m, 32, 64));
  return m;
}

__device__ __forceinline__ int dot4_i8(u32 a, u32 b, int acc) {
#if __has_builtin(__builtin_amdgcn_sdot4)
  return __builtin_amdgcn_sdot4((int)a, (int)b, acc, false);
#else
  acc += ((int)(a << 24) >> 24) * ((int)(b << 24) >> 24);
  acc += ((int)(a << 16) >> 24) * ((int)(b << 16) >> 24);
  acc += ((int)(a << 8) >> 24)  * ((int)(b << 8) >> 24);
  acc += ((int)a >> 24)         * ((int)b >> 24);
  return acc;
#endif
}

// ---------------- int8 group-scale path ----------------
// embq: [T][16] u32 (64 int8/row = 1 line); escale_g: [ngE] f16 (scale = m/127)
// phq:  [P][16] u32;                        pscale_g: [ngP] f16

// A (fused): one block per 64-row group (4096 floats, 16 KB contiguous).
__global__ void __launch_bounds__(256) quant_emb_fused_kernel(
    const float* __restrict__ emb,
    u32* __restrict__ embq,
    __half* __restrict__ escale_g,
    long total /* = T*D floats */) {
  long base = (long)blockIdx.x * (GRP * D);
  f32x4 v[4];
  float m = 0.f;
#pragma unroll
  for (int k = 0; k < 4; ++k) {
    long off = base + (long)k * 1024 + (long)threadIdx.x * 4;
    if (off < total) {
      v[k] = __builtin_nontemporal_load((const f32x4*)(emb + off));
      m = fmaxf(m, fmaxf(fmaxf(fabsf(v[k].x), fabsf(v[k].y)),
                         fmaxf(fabsf(v[k].z), fabsf(v[k].w))));
    } else {
      v[k] = (f32x4){0.f, 0.f, 0.f, 0.f};
    }
  }
  m = wave_max(m);
  __shared__ float red[4];
  __shared__ float bscale;
  if ((threadIdx.x & 63) == 0) red[threadIdx.x >> 6] = m;
  __syncthreads();
  if (threadIdx.x == 0) {
    float mm = fmaxf(fmaxf(red[0], red[1]), fmaxf(red[2], red[3]));
    __half h = __float2half(mm * (1.f / 127.f));
    escale_g[blockIdx.x] = h;
    bscale = __half2float(h);          // roundtripped for consistency
  }
  __syncthreads();
  float sv = bscale;
  float inv = (sv > 0.f) ? 1.f / sv : 0.f;
#pragma unroll
  for (int k = 0; k < 4; ++k) {
    long off = base + (long)k * 1024 + (long)threadIdx.x * 4;
    if (off < total) {
      int q0 = __float2int_rn(v[k].x * inv);
      int q1 = __float2int_rn(v[k].y * inv);
      int q2 = __float2int_rn(v[k].z * inv);
      int q3 = __float2int_rn(v[k].w * inv);
      u32 w = (u32)(q0 & 0xFF) | ((u32)(q1 & 0xFF) << 8) |
              ((u32)(q2 & 0xFF) << 16) | ((u32)(q3 & 0xFF) << 24);
      __builtin_nontemporal_store(w, embq + (off >> 2));
    }
  }
}

// B: build + quantize ph, one block per 64-ph-row group (block-local scale).
__global__ void __launch_bounds__(256) ph_build_kernel(
    const u32* __restrict__ embq,
    const __half* __restrict__ escale_g,
    const int* __restrict__ sampled,   // [P,2]
    u32* __restrict__ phq,
    __half* __restrict__ pscale_g,
    int P) {
  int g = blockIdx.x;
  int r = threadIdx.x >> 2;     // row within group
  int l = threadIdx.x & 3;
  int p = g * GRP + r;
  bool valid = (p < P);
  float f[16];
  float m = 0.f;
  if (valid) {
    int s0 = sampled[2 * p + 0];
    int s1 = sampled[2 * p + 1];
    u32x4 q0 = *(const u32x4*)(embq + (size_t)s0 * 16 + l * 4);
    u32x4 q1 = *(const u32x4*)(embq + (size_t)s1 * 16 + l * 4);
    float c0 = 0.5f * __half2float(escale_g[s0 >> 6]);
    float c1 = 0.5f * __half2float(escale_g[s1 >> 6]);
#pragma unroll
    for (int k = 0; k < 4; ++k) {
      u32 a = q0[k], b = q1[k];
      f[4 * k + 0] = c0 * (float)((int)(a << 24) >> 24) + c1 * (float)((int)(b << 24) >> 24);
      f[4 * k + 1] = c0 * (float)((int)(a << 16) >> 24) + c1 * (float)((int)(b << 16) >> 24);
      f[4 * k + 2] = c0 * (float)((int)(a << 8) >> 24)  + c1 * (float)((int)(b << 8) >> 24);
      f[4 * k + 3] = c0 * (float)((int)a >> 24)         + c1 * (float)((int)b >> 24);
    }
#pragma unroll
    for (int i = 0; i < 16; ++i) m = fmaxf(m, fabsf(f[i]));
  } else {
#pragma unroll
    for (int i = 0; i < 16; ++i) f[i] = 0.f;
  }
  m = wave_max(m);
  __shared__ float red[4];
  __shared__ float bscale;
  if ((threadIdx.x & 63) == 0) red[threadIdx.x >> 6] = m;
  __syncthreads();
  if (threadIdx.x == 0) {
    float mm = fmaxf(fmaxf(red[0], red[1]), fmaxf(red[2], red[3]));
    __half h = __float2half(mm * (1.f / 127.f));
    pscale_g[g] = h;
    bscale = __half2float(h);
  }
  __syncthreads();
  if (valid) {
    float sv = bscale;
    float inv = (sv > 0.f) ? 1.f / sv : 0.f;
    u32x4 w;
#pragma unroll
    for (int k = 0; k < 4; ++k) {
      int a0 = __float2int_rn(f[4 * k + 0] * inv);
      int a1 = __float2int_rn(f[4 * k + 1] * inv);
      int a2 = __float2int_rn(f[4 * k + 2] * inv);
      int a3 = __float2int_rn(f[4 * k + 3] * inv);
      w[k] = (u32)(a0 & 0xFF) | ((u32)(a1 & 0xFF) << 8) |
             ((u32)(a2 & 0xFF) << 16) | ((u32)(a3 & 0xFF) << 24);
    }
    *(u32x4*)(phq + (size_t)p * 16 + l * 4) = w;
  }
}

// C: edge scores. 4 lanes x 4 edges per thread; 2-stage counted-vmcnt
// pipeline (8 gathers in flight, vmcnt(4) -> e0/e1, vmcnt(0) -> e2/e3).
// Scales in LDS (lgkmcnt-decoupled); embq gathers sc1+nt (L2 bypass);
// output as one coalesced float4 store per quad.
__global__ void __launch_bounds__(256) edge_score_kernel(
    const u32* __restrict__ phq,
    const __half* __restrict__ pscale_g,
    const u32* __restrict__ embq,
    const __half* __restrict__ escale_g,
    const int* __restrict__ esrc,
    const int* __restrict__ edst,
    float* __restrict__ out,
    int E, int ngE, int ngP) {
  __shared__ __half lds_es[NG_E_MAX];
  __shared__ __half lds_ps[NG_P_MAX];
  for (int i = threadIdx.x; i < ngE; i += 256) lds_es[i] = escale_g[i];
  for (int i = threadIdx.x; i < ngP; i += 256) lds_ps[i] = pscale_g[i];
  __syncthreads();

  long nQuad = ((long)E + 3) >> 2;
  long total = nQuad * 4;                 // (quad, lane) work items
  long stride = (long)gridDim.x * 256;
  for (long idx = (long)blockIdx.x * 256 + threadIdx.x; idx < total; idx += stride) {
    long quad = idx >> 2;
    int l = (int)(idx & 3);
    int e0 = (int)(quad << 2);

    if (e0 + 3 < E) {
      // ---- fast path: 4 edges, pipelined ----
      i32x4 sv = __builtin_nontemporal_load((const i32x4*)(esrc + e0));
      i32x4 dv = __builtin_nontemporal_load((const i32x4*)(edst + e0));

      const u32* pa0 = phq  + (size_t)sv.x * 16 + l * 4;
      const u32* ea0 = embq + (size_t)dv.x * 16 + l * 4;
      const u32* pa1 = phq  + (size_t)sv.y * 16 + l * 4;
      const u32* ea1 = embq + (size_t)dv.y * 16 + l * 4;
      const u32* pa2 = phq  + (size_t)sv.z * 16 + l * 4;
      const u32* ea2 = embq + (size_t)dv.z * 16 + l * 4;
      const u32* pa3 = phq  + (size_t)sv.w * 16 + l * 4;
      const u32* ea3 = embq + (size_t)dv.w * 16 + l * 4;

      u32x4 qp0, qp1, qp2, qp3, qe0, qe1, qe2, qe3;
      asm volatile("global_load_dwordx4 %0, %1, off"        : "=&v"(qp0) : "v"(pa0));
      asm volatile("global_load_dwordx4 %0, %1, off sc1 nt" : "=&v"(qe0) : "v"(ea0));
      asm volatile("global_load_dwordx4 %0, %1, off"        : "=&v"(qp1) : "v"(pa1));
      asm volatile("global_load_dwordx4 %0, %1, off sc1 nt" : "=&v"(qe1) : "v"(ea1));
      asm volatile("global_load_dwordx4 %0, %1, off"        : "=&v"(qp2) : "v"(pa2));
      asm volatile("global_load_dwordx4 %0, %1, off sc1 nt" : "=&v"(qe2) : "v"(ea2));
      asm volatile("global_load_dwordx4 %0, %1, off"        : "=&v"(qp3) : "v"(pa3));
      asm volatile("global_load_dwordx4 %0, %1, off sc1 nt" : "=&v"(qe3) : "v"(ea3));

      // stage 1: oldest 4 loads (e0, e1) done; e2/e3 still in flight
      asm volatile("s_waitcnt vmcnt(4)"
                   : "+v"(qp0), "+v"(qe0), "+v"(qp1), "+v"(qe1) :: "memory");
      __builtin_amdgcn_sched_barrier(0);
      int a0 = 0, a1 = 0;
#pragma unroll
      for (int k = 0; k < 4; ++k) {
        a0 = dot4_i8(qp0[k], qe0[k], a0);
        a1 = dot4_i8(qp1[k], qe1[k], a1);
      }
      a0 += __shfl_xor(a0, 1, 64);
      a0 += __shfl_xor(a0, 2, 64);
      a1 += __shfl_xor(a1, 1, 64);
      a1 += __shfl_xor(a1, 2, 64);

      // stage 2: drain remaining loads (e2, e3)
      asm volatile("s_waitcnt vmcnt(0)"
                   : "+v"(qp2), "+v"(qe2), "+v"(qp3), "+v"(qe3) :: "memory");
      __builtin_amdgcn_sched_barrier(0);
      int a2 = 0, a3 = 0;
#pragma unroll
      for (int k = 0; k < 4; ++k) {
        a2 = dot4_i8(qp2[k], qe2[k], a2);
        a3 = dot4_i8(qp3[k], qe3[k], a3);
      }
      a2 += __shfl_xor(a2, 1, 64);
      a2 += __shfl_xor(a2, 2, 64);
      a3 += __shfl_xor(a3, 1, 64);
      a3 += __shfl_xor(a3, 2, 64);

      if (l == 0) {
        f32x4 o;
        o.x = (float)a0 * __half2float(lds_ps[sv.x >> 6]) * __half2float(lds_es[dv.x >> 6]);
        o.y = (float)a1 * __half2float(lds_ps[sv.y >> 6]) * __half2float(lds_es[dv.y >> 6]);
        o.z = (float)a2 * __half2float(lds_ps[sv.z >> 6]) * __half2float(lds_es[dv.z >> 6]);
        o.w = (float)a3 * __half2float(lds_ps[sv.w >> 6]) * __half2float(lds_es[dv.w >> 6]);
        __builtin_nontemporal_store(o, (f32x4*)(out + e0));
      }
    } else {
      // ---- tail: per-edge scalar path ----
      for (int e = e0; e < E; ++e) {
        int s = esrc[e];
        int d = edst[e];
        const u32* pa = phq  + (size_t)s * 16 + l * 4;
        const u32* ea = embq + (size_t)d * 16 + l * 4;
        u32x4 qp, qe;
        asm volatile("global_load_dwordx4 %0, %1, off"        : "=&v"(qp) : "v"(pa));
        asm volatile("global_load_dwordx4 %0, %1, off sc1 nt" : "=&v"(qe) : "v"(ea));
        asm volatile("s_waitcnt vmcnt(0)" : "+v"(qp), "+v"(qe) :: "memory");
        __builtin_amdgcn_sched_barrier(0);
        int a = 0;
#pragma unroll
        for (int k = 0; k < 4; ++k) a = dot4_i8(qp[k], qe[k], a);
        a += __shfl_xor(a, 1, 64);
        a += __shfl_xor(a, 2, 64);
        if (l == 0) {
          float o = (float)a * __half2float(lds_ps[s >> 6]) *
                    __half2float(lds_es[d >> 6]);
          out[e] = o;
        }
      }
    }
  }
}

// ---------------- f32 fallback (ws too small / sizes exceed LDS tables) ----

__global__ void __launch_bounds__(256) ph_build_f32_kernel(
    const float* __restrict__ track_emb, const int* __restrict__ sampled,
    float* __restrict__ ph, int P) {
  int tid = blockIdx.x * blockDim.x + threadIdx.x;
  int p = tid >> 4, l = tid & 15;
  if (p >= P) return;
  int s0 = sampled[2 * p + 0], s1 = sampled[2 * p + 1];
  const float4 a = *(const float4*)(track_emb + (size_t)s0 * D + l * 4);
  const float4 b = *(const float4*)(track_emb + (size_t)s1 * D + l * 4);
  float4 r;
  r.x = 0.5f * (a.x + b.x); r.y = 0.5f * (a.y + b.y);
  r.z = 0.5f * (a.z + b.z); r.w = 0.5f * (a.w + b.w);
  *(float4*)(ph + (size_t)p * D + l * 4) = r;
}

__global__ void __launch_bounds__(256) edge_score_f32_kernel(
    const float* __restrict__ ph, const float* __restrict__ track_emb,
    const int* __restrict__ esrc, const int* __restrict__ edst,
    float* __restrict__ out, int E) {
  int tid = blockIdx.x * blockDim.x + threadIdx.x;
  int e = tid >> 4, l = tid & 15;
  if (e >= E) return;
  int s = esrc[e], d = edst[e];
  const float4 a = *(const float4*)(ph + (size_t)s * D + l * 4);
  const float4 b = *(const float4*)(track_emb + (size_t)d * D + l * 4);
  float v = a.x * b.x + a.y * b.y + a.z * b.z + a.w * b.w;
  v += __shfl_xor(v, 1, 64);
  v += __shfl_xor(v, 2, 64);
  v += __shfl_xor(v, 4, 64);
  if (l == 0) out[e] = v;
}

extern "C" void kernel_launch(void* const* d_in, const int* in_sizes, int n_in,
                              void* d_out, int out_size, void* d_ws, size_t ws_size,
                              hipStream_t stream) {
  const float* track_emb = (const float*)d_in[0];   // [T, 64] f32
  const int*   edge_src  = (const int*)d_in[1];     // [E]
  const int*   edge_dst  = (const int*)d_in[2];     // [E]
  const int*   sampled   = (const int*)d_in[3];     // [P, 2]
  float* out = (float*)d_out;                       // [E] f32

  const int E = in_sizes[1];
  const int P = in_sizes[3] / 2;
  const int T = in_sizes[0] / D;

  const int ngE = (T + GRP - 1) / GRP;
  const int ngP = (P + GRP - 1) / GRP;

  const size_t embq_bytes   = (size_t)T * 16 * sizeof(u32);          // 32 MB
  const size_t escale_bytes = ((size_t)ngE * 2 + 255) & ~(size_t)255;
  const size_t phq_bytes    = (size_t)P * 16 * sizeof(u32);          // 6.4 MB
  const size_t pscale_bytes = ((size_t)ngP * 2 + 255) & ~(size_t)255;
  const size_t need = embq_bytes + escale_bytes + phq_bytes + pscale_bytes;

  if (ws_size >= need && ngE <= NG_E_MAX && ngP <= NG_P_MAX) {
    char* w = (char*)d_ws;
    u32*    embq     = (u32*)w;     w += embq_bytes;
    __half* escale_g = (__half*)w;  w += escale_bytes;
    u32*    phq      = (u32*)w;     w += phq_bytes;
    __half* pscale_g = (__half*)w;

    // A: fused group-absmax + quantize, ONE pass over emb
    quant_emb_fused_kernel<<<ngE, 256, 0, stream>>>(track_emb, embq, escale_g,
                                                    (long)T * D);
    // B: build + quantize ph (block-local group scale)
    ph_build_kernel<<<ngP, 256, 0, stream>>>(embq, escale_g, sampled,
                                             phq, pscale_g, P);
    // C: edge scores, grid-stride, 4 edges/thread pipelined
    {
      long nQuad = ((long)E + 3) >> 2;
      long total = nQuad * 4;
      int blocks = (int)((total + 255) / 256);
      if (blocks > 2048) blocks = 2048;
      edge_score_kernel<<<blocks, 256, 0, stream>>>(
          phq, pscale_g, embq, escale_g, edge_src, edge_dst, out, E, ngE, ngP);
    }
  } else {
    // fallback: f32 path
    float* ph = (float*)d_ws;
    {
      long t = (long)P * 16;
      int blocks = (int)((t + 255) / 256);
      ph_build_f32_kernel<<<blocks, 256, 0, stream>>>(track_emb, sampled, ph, P);
    }
    {
      long t = (long)E * 16;
      int blocks = (int)((t + 255) / 256);
      edge_score_f32_kernel<<<blocks, 256, 0, stream>>>(ph, track_emb, edge_src,
                                                        edge_dst, out, E);
    }
  }
}